// Round 12
// baseline (265.204 us; speedup 1.0000x reference)
//
#include <hip/hip_runtime.h>

#define DEV __device__ __forceinline__

typedef __attribute__((ext_vector_type(8))) short sv8;   // 8 x bf16 bits
typedef __attribute__((ext_vector_type(4))) short sv4;
typedef __attribute__((ext_vector_type(4))) float f32x4;

// ---- bf16 helpers (bit-level, round-to-nearest-even) ----
DEV short f2bf(float f) {
  unsigned u = __float_as_uint(f);
  unsigned r = (u + 0x7fffu + ((u >> 16) & 1u)) >> 16;
  return (short)r;
}
DEV float bf2f(short s) {
  return __uint_as_float(((unsigned)(unsigned short)s) << 16);
}

// ---- async global -> LDS, 16B per lane. LDS dest = wave-uniform base + lane*16 ----
DEV void gload16(const void* g, void* l) {
  __builtin_amdgcn_global_load_lds((const __attribute__((address_space(1))) void*)g,
                                   (__attribute__((address_space(3))) void*)l, 16, 0, 0);
}

struct Args {
  const float *x, *ctx, *Wq, *Wk, *Wv1, *ln_g, *ln_b, *Wconv, *Wout;
  short *x_bf, *ctx_bf, *wq_bf, *wk_bf, *wv1_bf, *wout_bf;
  short *q_bf, *k_bf, *mid_bf, *op_bf;
  float *psum, *psumsq, *tbuf, *out;
};

// ================= K1: fp32 -> bf16 for 6 tensors, grid-stride =================
__global__ __launch_bounds__(256) void k_cvt(Args a) {
  const int gtid = blockIdx.x * 256 + threadIdx.x;
  const int T = gridDim.x * 256;
  for (int i = gtid; i < 1721856; i += T) {   // float4 units, cumulative ends
    const float* s; short* d; int base;
    if      (i < 98304)   { s = a.x;    d = a.x_bf;    base = 0; }
    else if (i < 493056)  { s = a.ctx;  d = a.ctx_bf;  base = 98304; }
    else if (i < 640512)  { s = a.Wq;   d = a.wq_bf;   base = 493056; }
    else if (i < 787968)  { s = a.Wk;   d = a.wk_bf;   base = 640512; }
    else if (i < 1574400) { s = a.Wv1;  d = a.wv1_bf;  base = 787968; }
    else                  { s = a.Wout; d = a.wout_bf; base = 1574400; }
    int j = i - base;
    float4 v = ((const float4*)s)[j];
    sv4 o = { f2bf(v.x), f2bf(v.y), f2bf(v.z), f2bf(v.w) };
    ((sv4*)d)[j] = o;
  }
}

// ===== NT GEMM tile: C[M,N]=A[M,K]*B[N,K]^T, 128x128, BK=32, 2-phase dbuf ======
// MODE: 1 = bf16 store, 2 = f32 atomicAdd (split-K).
// STATS: also emit per-(64-col-half, row) partial Sum/SumSq of fp32 acc
// (each slot written exactly once -> deterministic, no zero-init needed).
template <int MODE, int SPLITK, int STATS>
DEV void gemm_tile(const short* __restrict__ A, const short* __restrict__ B,
                   void* __restrict__ C, float* __restrict__ psum,
                   float* __restrict__ psumsq,
                   int M, int N, int K, int bm, int bn, int ks) {
  __shared__ __align__(16) short As[2][4096];
  __shared__ __align__(16) short Bs[2][4096];
  const int tid = threadIdx.x;
  const int wave = tid >> 6, lane = tid & 63;
  const int wr = wave >> 1, wc = wave & 1;
  const int row0 = bm * 128, col0 = bn * 128;
  const int rsel = lane & 15;
  const int Am = M - 1, Bm = N - 1;
  const int lr = lane >> 2;
  const int c8 = ((lane & 3) ^ ((lane >> 2) & 3)) * 8;  // inverse-swizzled source slot
  const int Ksl = K / SPLITK;
  const int kbase = ks * Ksl;
  const int nt = Ksl / 32;

  const f32x4 z = {0.f, 0.f, 0.f, 0.f};
  f32x4 acc[4][4];
#pragma unroll
  for (int m = 0; m < 4; ++m)
#pragma unroll
    for (int n = 0; n < 4; ++n) acc[m][n] = z;

  auto stage = [&](int t, int buf) {
    int k0 = kbase + t * 32;
#pragma unroll
    for (int s = 0; s < 2; ++s) {
      int chunk = s * 4 + wave;            // wave-uniform LDS chunk
      int rr = chunk * 16 + lr;
      int gr = row0 + rr; if (gr > Am) gr = Am;
      gload16(A + (size_t)gr * K + k0 + c8, &As[buf][chunk * 512]);
      int gc = col0 + rr; if (gc > Bm) gc = Bm;
      gload16(B + (size_t)gc * K + k0 + c8, &Bs[buf][chunk * 512]);
    }
  };

  stage(0, 0);
  __syncthreads();
  const int ko = (((lane >> 4) ^ (rsel & 3)) * 8);  // swizzled read slot

  for (int t = 0; t < nt; ++t) {
    int cur = t & 1;
    if (t + 1 < nt) stage(t + 1, cur ^ 1);
    sv8 a[4], b[4];
#pragma unroll
    for (int m = 0; m < 4; ++m)
      a[m] = *(const sv8*)(&As[cur][(wr * 64 + m * 16 + rsel) * 32 + ko]);
#pragma unroll
    for (int n = 0; n < 4; ++n)
      b[n] = *(const sv8*)(&Bs[cur][(wc * 64 + n * 16 + rsel) * 32 + ko]);
#pragma unroll
    for (int m = 0; m < 4; ++m)
#pragma unroll
      for (int n = 0; n < 4; ++n)
        acc[m][n] = __builtin_amdgcn_mfma_f32_16x16x32_bf16(a[m], b[n], acc[m][n], 0, 0, 0);
    __syncthreads();
  }

  const int cc = lane & 15, cr = (lane >> 4) * 4;
#pragma unroll
  for (int m = 0; m < 4; ++m)
#pragma unroll
    for (int n = 0; n < 4; ++n) {
      int c = col0 + wc * 64 + n * 16 + cc;
#pragma unroll
      for (int j = 0; j < 4; ++j) {
        int r = row0 + wr * 64 + m * 16 + cr + j;
        if (r < M && c < N) {
          float v = acc[m][n][j];
          if (MODE == 1) ((short*)C)[(size_t)r * N + c] = f2bf(v);
          else           atomicAdd(&((float*)C)[(size_t)r * N + c], v);
        }
      }
    }

  if (STATS) {
    // per (m,j): Sum/SumSq over this wave's 64-col half (4 n-frags x 16 cc-lanes)
#pragma unroll
    for (int m = 0; m < 4; ++m)
#pragma unroll
      for (int j = 0; j < 4; ++j) {
        float s = 0.f, s2 = 0.f;
#pragma unroll
        for (int n = 0; n < 4; ++n) { float v = acc[m][n][j]; s += v; s2 += v * v; }
        s  += __shfl_xor(s, 1);  s2 += __shfl_xor(s2, 1);
        s  += __shfl_xor(s, 2);  s2 += __shfl_xor(s2, 2);
        s  += __shfl_xor(s, 4);  s2 += __shfl_xor(s2, 4);
        s  += __shfl_xor(s, 8);  s2 += __shfl_xor(s2, 8);
        int grow = row0 + wr * 64 + m * 16 + cr + j;
        if ((lane & 15) == 0 && grow < M) {
          int c64 = bn * 2 + wc;
          psum[(size_t)c64 * M + grow]   = s;
          psumsq[(size_t)c64 * M + grow] = s2;
        }
      }
  }
}

// ================= K2: q + k + mid GEMMs, 670 blocks (mid also emits stats) ====
__global__ __launch_bounds__(256) void k_gemm3(Args a) {
  const int bid = blockIdx.x;
  if (bid < 24) {
    gemm_tile<1, 1, 0>(a.x_bf, a.wq_bf, a.q_bf, nullptr, nullptr,
                       512, 768, 768, bid / 6, bid % 6, 0);
  } else if (bid < 126) {
    int local = bid - 24;
    gemm_tile<1, 1, 0>(a.ctx_bf, a.wk_bf, a.k_bf, nullptr, nullptr,
                       2056, 768, 768, local / 6, local % 6, 0);
  } else {
    int local = bid - 126;
    gemm_tile<1, 1, 1>(a.ctx_bf, a.wv1_bf, a.mid_bf, a.psum, a.psumsq,
                       2056, 4096, 768, local / 32, local % 32, 0);
  }
}

// ========== K3: per (b,q): finalize LN stats + VALU attention + folded-LN t ====
__global__ __launch_bounds__(256) void k_tk2(Args a) {
  __shared__ short ms[257][64];     // 32896 B mid slice
  __shared__ float qv[6][128];      // 3072 B  q rows (fp32)
  __shared__ float w[6][257];       // 6168 B  sim -> attn*rstd
  __shared__ float muld[257], rsld[257];
  __shared__ float wredA[6][4], wredB[6][4];
  __shared__ float c0sh[6], dinv[6];
  const int bq = blockIdx.x;
  const int b = bq >> 6, q = bq & 63;
  const int tid = threadIdx.x, wave = tid >> 6, lane = tid & 63;
  const float S2 = 0.08838834764831845f;  // 1/sqrt(128)

  // stage mid slice
  for (int lin = tid; lin < 257 * 8; lin += 256) {
    int j = lin >> 3, seg = (lin & 7) * 8;
    *(sv8*)(&ms[j][seg]) = *(const sv8*)(a.mid_bf + (size_t)(b * 257 + j) * 4096 + q * 64 + seg);
  }
  // stage q row as fp32
  for (int i = tid; i < 768; i += 256)
    qv[i >> 7][i & 127] = bf2f(a.q_bf[(size_t)(b * 64 + q) * 768 + i]);
  // finalize LN stats for this b's rows
  for (int j = tid; j < 257; j += 256) {
    int grow = b * 257 + j;
    float s = 0.f, s2 = 0.f;
#pragma unroll 8
    for (int c = 0; c < 64; ++c) {
      s  += a.psum[(size_t)c * 2056 + grow];
      s2 += a.psumsq[(size_t)c * 2056 + grow];
    }
    float mu = s * (1.0f / 4096.0f);
    float var = s2 * (1.0f / 4096.0f) - mu * mu;
    muld[j] = mu;
    rsld[j] = rsqrtf(var + 1e-5f);
  }
  __syncthreads();

  // sim[h][j] = (q_h . k_jh) * S2  (VALU; each thread owns its j's)
  for (int j = tid; j < 257; j += 256) {
    const short* kr = a.k_bf + (size_t)(b * 257 + j) * 768;
    float acc6[6];
#pragma unroll
    for (int h = 0; h < 6; ++h) {
      float s = 0.f;
#pragma unroll
      for (int db = 0; db < 16; ++db) {
        sv8 kk = *(const sv8*)(kr + h * 128 + db * 8);
        const float4* qp = (const float4*)&qv[h][db * 8];
        float4 q0 = qp[0], q1 = qp[1];
        s += q0.x * bf2f(kk[0]); s += q0.y * bf2f(kk[1]);
        s += q0.z * bf2f(kk[2]); s += q0.w * bf2f(kk[3]);
        s += q1.x * bf2f(kk[4]); s += q1.y * bf2f(kk[5]);
        s += q1.z * bf2f(kk[6]); s += q1.w * bf2f(kk[7]);
      }
      acc6[h] = s * S2;
    }
#pragma unroll
    for (int h = 0; h < 6; ++h) w[h][j] = acc6[h];
  }

  // softmax: per-h max (own-j partials -> wave tree -> cross-wave)
  float p[6];
#pragma unroll
  for (int h = 0; h < 6; ++h) p[h] = -1e30f;
  for (int j = tid; j < 257; j += 256)
#pragma unroll
    for (int h = 0; h < 6; ++h) p[h] = fmaxf(p[h], w[h][j]);
#pragma unroll
  for (int h = 0; h < 6; ++h) {
#pragma unroll
    for (int off = 32; off; off >>= 1) p[h] = fmaxf(p[h], __shfl_xor(p[h], off));
    if (lane == 0) wredA[h][wave] = p[h];
  }
  __syncthreads();
  float mx[6];
#pragma unroll
  for (int h = 0; h < 6; ++h)
    mx[h] = fmaxf(fmaxf(wredA[h][0], wredA[h][1]), fmaxf(wredA[h][2], wredA[h][3]));
  __syncthreads();

  // exp + per-h denom
#pragma unroll
  for (int h = 0; h < 6; ++h) p[h] = 0.f;
  for (int j = tid; j < 257; j += 256)
#pragma unroll
    for (int h = 0; h < 6; ++h) {
      float e = __expf(w[h][j] - mx[h]);
      w[h][j] = e;
      p[h] += e;
    }
#pragma unroll
  for (int h = 0; h < 6; ++h) {
#pragma unroll
    for (int off = 32; off; off >>= 1) p[h] += __shfl_xor(p[h], off);
    if (lane == 0) wredB[h][wave] = p[h];
  }
  __syncthreads();
  if (tid < 6)
    dinv[tid] = 1.f / (wredB[tid][0] + wredB[tid][1] + wredB[tid][2] + wredB[tid][3]);
  __syncthreads();

  // w = attn * rstd; c0[h] = sum_j w*mu  (Sum_j attn == 1, so beta term uses 1)
#pragma unroll
  for (int h = 0; h < 6; ++h) p[h] = 0.f;
  for (int j = tid; j < 257; j += 256) {
    float rsj = rsld[j], muj = muld[j];
#pragma unroll
    for (int h = 0; h < 6; ++h) {
      float wv = w[h][j] * dinv[h] * rsj;
      w[h][j] = wv;
      p[h] += wv * muj;
    }
  }
#pragma unroll
  for (int h = 0; h < 6; ++h) {
#pragma unroll
    for (int off = 32; off; off >>= 1) p[h] += __shfl_xor(p[h], off);
    if (lane == 0) wredA[h][wave] = p[h];
  }
  __syncthreads();
  if (tid < 6)
    c0sh[tid] = wredA[tid][0] + wredA[tid][1] + wredA[tid][2] + wredA[tid][3];
  __syncthreads();

  // t-loop: 384 (h,r) items, 4 independent accumulators
  for (int idx = tid; idx < 384; idx += 256) {
    const int h = idx >> 6, r = idx & 63;
    float s0 = 0.f, s1 = 0.f, s2 = 0.f, s3 = 0.f;
    for (int j = 0; j < 256; j += 4) {
      s0 += w[h][j]     * bf2f(ms[j][r]);
      s1 += w[h][j + 1] * bf2f(ms[j + 1][r]);
      s2 += w[h][j + 2] * bf2f(ms[j + 2][r]);
      s3 += w[h][j + 3] * bf2f(ms[j + 3][r]);
    }
    float stot = (s0 + s1) + (s2 + s3) + w[h][256] * bf2f(ms[256][r]);
    float out = a.ln_g[q * 64 + r] * (stot - c0sh[h]) + a.ln_b[q * 64 + r];
    a.tbuf[((size_t)(b * 6 + h) * 64 + q) * 64 + r] = out;
  }
}

// ====== K4: vproj (blocks 0-191) + zero d_out for split-K atomics (192-575) =====
__global__ __launch_bounds__(256) void k_vproj(Args a) {
  const int bid = blockIdx.x, tid = threadIdx.x;
  if (bid >= 192) {
    int i = (bid - 192) * 256 + tid;   // 384 blocks x 256 float4 = 393216 floats
    ((float4*)a.out)[i] = make_float4(0.f, 0.f, 0.f, 0.f);
    return;
  }
  __shared__ float ts[48][64];
  const int q = bid / 3, chunk = bid % 3;
  for (int lin = tid; lin < 48 * 64; lin += 256) {
    int bh = lin >> 6, r = lin & 63;
    ts[bh][r] = a.tbuf[((size_t)bh * 64 + q) * 64 + r];
  }
  __syncthreads();
  const int d = chunk * 256 + tid;
  const int h = d >> 7;  // wave-uniform
  const float4* w4 = (const float4*)(a.Wconv + ((size_t)q * 768 + d) * 64);
  float acc[8] = {0.f, 0.f, 0.f, 0.f, 0.f, 0.f, 0.f, 0.f};
#pragma unroll
  for (int r4 = 0; r4 < 16; ++r4) {
    float4 wv = w4[r4];
#pragma unroll
    for (int bb = 0; bb < 8; ++bb) {
      acc[bb] += wv.x * ts[bb * 6 + h][r4 * 4 + 0];
      acc[bb] += wv.y * ts[bb * 6 + h][r4 * 4 + 1];
      acc[bb] += wv.z * ts[bb * 6 + h][r4 * 4 + 2];
      acc[bb] += wv.w * ts[bb * 6 + h][r4 * 4 + 3];
    }
  }
#pragma unroll
  for (int bb = 0; bb < 8; ++bb)
    a.op_bf[((size_t)(bb * 64 + q)) * 768 + d] = f2bf(acc[bb]);
}

// ================= K5: out = op @ Wout^T, split-K=4 atomic into zeroed d_out ====
__global__ __launch_bounds__(256) void k_outk(Args a) {
  gemm_tile<2, 4, 0>(a.op_bf, a.wout_bf, a.out, nullptr, nullptr,
                     512, 768, 768, blockIdx.x, blockIdx.y, blockIdx.z);
}

extern "C" void kernel_launch(void* const* d_in, const int* in_sizes, int n_in,
                              void* d_out, int out_size, void* d_ws, size_t ws_size,
                              hipStream_t stream) {
  (void)in_sizes; (void)n_in; (void)out_size; (void)ws_size;

  char* ws = (char*)d_ws;
  size_t off = 0;
  auto alloc = [&](size_t bytes) -> void* {
    void* p = (void*)(ws + off);
    off += (bytes + 255) & ~(size_t)255;
    return p;
  };

  Args a;
  a.x    = (const float*)d_in[0];
  a.ctx  = (const float*)d_in[1];
  a.Wq   = (const float*)d_in[2];
  a.Wk   = (const float*)d_in[3];
  a.Wv1  = (const float*)d_in[4];
  a.ln_g = (const float*)d_in[5];
  a.ln_b = (const float*)d_in[6];
  a.Wconv = (const float*)d_in[7];
  a.Wout = (const float*)d_in[8];
  a.out  = (float*)d_out;

  a.x_bf    = (short*)alloc((size_t)393216 * 2);
  a.ctx_bf  = (short*)alloc((size_t)1579008 * 2);
  a.wq_bf   = (short*)alloc((size_t)589824 * 2);
  a.wk_bf   = (short*)alloc((size_t)589824 * 2);
  a.wv1_bf  = (short*)alloc((size_t)3145728 * 2);
  a.wout_bf = (short*)alloc((size_t)589824 * 2);
  a.q_bf    = (short*)alloc((size_t)393216 * 2);
  a.k_bf    = (short*)alloc((size_t)1579008 * 2);
  a.mid_bf  = (short*)alloc((size_t)8421376 * 2);
  a.psum    = (float*)alloc((size_t)64 * 2056 * 4);
  a.psumsq  = (float*)alloc((size_t)64 * 2056 * 4);
  a.tbuf    = (float*)alloc((size_t)196608 * 4);
  a.op_bf   = (short*)alloc((size_t)393216 * 2);

  // 1. fp32 -> bf16
  k_cvt<<<dim3(2048), dim3(256), 0, stream>>>(a);
  // 2. q + k + mid GEMMs (mid blocks also emit LN-stat partials)
  k_gemm3<<<dim3(670), dim3(256), 0, stream>>>(a);
  // 3. stats-finalize + VALU attention + folded-LN t-contraction
  k_tk2<<<dim3(512), dim3(256), 0, stream>>>(a);
  // 4. Wconv expansion + zero d_out
  k_vproj<<<dim3(576), dim3(256), 0, stream>>>(a);
  // 5. out GEMM, split-K=4 atomic
  k_outk<<<dim3(4, 6, 4), dim3(256), 0, stream>>>(a);
}